// Round 14
// baseline (284.196 us; speedup 1.0000x reference)
//
#include <hip/hip_runtime.h>
#include <hip/hip_bf16.h>

// ---------------------------------------------------------------------------
// GINE GNN. Features: f16 plane (self/MLP) + fp8-e4m3 shadow plane gathered
// by k_agg (r8 layout: wave = 4 nodes x 16 lanes, 16-deep gather pipeline).
// CSR: single-pass bucket binning (256-node buckets, line-aligned
// reservations, EPB 2048 -> 782 blocks ~3/CU; r12 proved block-TLP is the
// bin2 lever) + per-bucket sort (1024 thr, 8 slots/thread) with register
// staging + direct pairs writes; graph-segment prep rides in k_prep.
// MLP epilogues vectorized via swizzled-LDS -> f16x8 + packed-fp8 (r13).
// Lessons: r2/r11 = cross-XCD fine-grain scatter/atomics kill; r4 = never
// trade reg accumulation for LDS atomics; r8 = gather MLP depth is the agg
// lever; r9 = agg+MLP fusion net-neutral; r10/r12 = line-dense reservations
// + all-CU grids fixed bin2; r13 = vector epilogues (-23us).
// ---------------------------------------------------------------------------

#define HID 128
#define NCLS 3
#define EPB 2048          // edges per binning block (782 blocks, ~3/CU)
#define BSHIFT 8          // bucket = dst >> 8 (256 nodes/bucket)
#define BNODES 256
#define ECAP 7500         // slots per bucket (mean padded ~6694, +8 sigma)

typedef _Float16 f16;
typedef f16 f16x2 __attribute__((ext_vector_type(2)));
typedef f16 f16x8 __attribute__((ext_vector_type(8)));
typedef float f32x2 __attribute__((ext_vector_type(2)));
typedef float f32x4 __attribute__((ext_vector_type(4)));
typedef unsigned short ushort;

__device__ __forceinline__ float bcf(int v) {
    return __builtin_bit_cast(float, v);
}
__device__ __forceinline__ float f16bits2f(ushort u) {
    return (float)__builtin_bit_cast(f16, u);
}

// ---- CSR build: ONE pass count+reserve(line-aligned)+place ----------------
// ebuf slot: x = src | (dstlocal<<24)  (sentinel -1 impossible: src < 2^24)
//            y = (attr_f16<<16) | msg0_f16

__global__ __launch_bounds__(1024) void k_bin2(const int* __restrict__ src,
                                               const int* __restrict__ dst,
                                               const float* __restrict__ eattr,
                                               const float* __restrict__ x,
                                               int* __restrict__ cursor,
                                               int2* __restrict__ ebuf,
                                               int E, int NB) {
    __shared__ int lh[512];
    __shared__ int lbase[512];
    __shared__ int lrsv[512];
    int t = threadIdx.x;
    if (t < NB) lh[t] = 0;
    __syncthreads();
    int base = blockIdx.x * EPB;
    int myd[2];
    #pragma unroll
    for (int j = 0; j < 2; ++j) {
        int e = base + j * 1024 + t;
        myd[j] = (e < E) ? dst[e] : -1;
        if (myd[j] >= 0) atomicAdd(&lh[myd[j] >> BSHIFT], 1);
    }
    __syncthreads();
    if (t < NB) {
        int c = lh[t];
        int cp = (c + 7) & ~7;           // 64B-line-aligned reservation
        lrsv[t] = cp;
        lbase[t] = (cp > 0) ? (t * ECAP + atomicAdd(&cursor[t], cp)) : 0;
        lh[t] = 0;
    }
    __syncthreads();
    #pragma unroll
    for (int j = 0; j < 2; ++j) {
        if (myd[j] >= 0) {
            int e = base + j * 1024 + t;
            int b = myd[j] >> BSHIFT;
            int s = src[e];
            float at = eattr[e];
            float msg = fmaxf(x[s] + at, 0.f);   // layer-0 message, hidden
            unsigned a16 = __builtin_bit_cast(ushort, (f16)at);
            unsigned m16 = __builtin_bit_cast(ushort, (f16)msg);
            int r = atomicAdd(&lh[b], 1);
            int pos = lbase[b] + r;
            if (pos < (b + 1) * ECAP)          // overflow guard (never hits)
                ebuf[pos] = make_int2(s | ((myd[j] & (BNODES - 1)) << 24),
                                      (int)((a16 << 16) | m16));
        }
    }
    __syncthreads();
    // sentinel-fill this block's padding (<=7 per bucket, own lines)
    if (t < NB) {
        int c = lh[t], cp = lrsv[t];
        int p0 = lbase[t] + c;
        int pe = lbase[t] + cp;
        int cap = (t + 1) * ECAP;
        if (pe > cap) pe = cap;
        for (int pos = p0; pos < pe; ++pos)
            ebuf[pos] = make_int2(-1, 0);
    }
}

// ---- prep: blocks 0..13 = W prefragmentation; block 14 = bucket scan;
// blocks 15+ = graph-segment prep (kept out of k_fill2's critical path).

__global__ __launch_bounds__(1024) void k_prep(const float* __restrict__ W2_0,
                                               const float* __restrict__ W1_s,
                                               const float* __restrict__ W2_s,
                                               f16* __restrict__ Wf,
                                               const int* __restrict__ cursor,
                                               int* __restrict__ bbase,
                                               const int* __restrict__ batch,
                                               int* __restrict__ gcount,
                                               int* __restrict__ gstart,
                                               int NB, int N) {
    int t = threadIdx.x;
    if (blockIdx.x < 14) {
        int id = blockIdx.x * 1024 + t;         // [0, 14336)
        int lane = id & 63;
        int w    = (id >> 6) & 3;
        int nf   = (id >> 8) & 1;
        int kk   = (id >> 9) & 3;
        int g    = id >> 11;
        const float* W = (g == 0) ? W2_0
                       : ((g & 1) ? W1_s + (size_t)((g - 1) >> 1) * HID * HID
                                  : W2_s + (size_t)((g - 2) >> 1) * HID * HID);
        int col = w * 32 + nf * 16 + (lane & 15);
        int k0  = kk * 32 + (lane >> 4) * 8;
        f16x8 hi;
        #pragma unroll
        for (int j = 0; j < 8; ++j)
            hi[j] = (f16)W[(k0 + j) * HID + col];
        size_t o = ((((size_t)g * 4 + kk) * 2 + nf) * 4 + w) * 512 +
                   (size_t)lane * 8;
        *(f16x8*)&Wf[o] = hi;
    } else if (blockIdx.x == 14) {
        __shared__ int sd[1024];
        int v = (t < NB) ? min(cursor[t], ECAP) : 0;
        sd[t] = v;
        __syncthreads();
        #pragma unroll
        for (int o = 1; o < 1024; o <<= 1) {
            int add = (t >= o) ? sd[t - o] : 0;
            __syncthreads();
            sd[t] += add;
            __syncthreads();
        }
        if (t < NB) bbase[t] = sd[t] - v;
        if (t == 1023) bbase[NB] = sd[1023];
    } else {
        int i = (blockIdx.x - 15) * 1024 + t;
        if (i < N) {
            int gb = batch[i];
            atomicAdd(&gcount[gb], 1);
            if (i == 0 || batch[i - 1] != gb) gstart[gb] = i;
        }
    }
}

// per-bucket (256 nodes): global read into REGISTERS (<=8 slots per thread,
// 1024 threads, statically unrolled); skip sentinels; count via LDS atomics;
// scan of 256 counters by wave 0 via shfl (4 counters/lane); place DIRECTLY
// to global pairs (block-exclusive region -> L2-absorbed, written once).
// pairs.x = src*128 byte offset (fp8 plane); pairs.y = f32 attr bits.
__global__ __launch_bounds__(1024) void k_fill2(const int2* __restrict__ ebuf,
                                               const int* __restrict__ btot,
                                               const int* __restrict__ bbase,
                                               const float* __restrict__ x,
                                               int2* __restrict__ meta,
                                               int2* __restrict__ pairs,
                                               float* __restrict__ hin0,
                                               int N) {
    __shared__ int lcnt[BNODES];
    __shared__ int lofs[BNODES];
    __shared__ float satom[BNODES];
    int b = blockIdx.x, t = threadIdx.x;
    int estart = b * ECAP;
    int cnt = min(btot[b], ECAP);
    int pstart = bbase[b];
    int nb0 = b << BSHIFT;
    if (t < BNODES) {
        lcnt[t] = 0;
        satom[t] = 0.f;
    }
    __syncthreads();
    // load slots into registers: 8 independent loads in flight, then count
    int2 myv[8];
    #pragma unroll
    for (int j = 0; j < 8; ++j) {
        int i = j * 1024 + t;
        if (i < cnt) myv[j] = ebuf[estart + i];
    }
    #pragma unroll
    for (int j = 0; j < 8; ++j) {
        int i = j * 1024 + t;
        if (i < cnt && myv[j].x != -1)
            atomicAdd(&lcnt[((unsigned)myv[j].x) >> 24], 1);
    }
    __syncthreads();
    // wave 0 scans the 256 counters via shfl (4 counters/lane)
    if (t < 64) {
        int c0 = lcnt[4 * t], c1 = lcnt[4 * t + 1];
        int c2 = lcnt[4 * t + 2], c3 = lcnt[4 * t + 3];
        int s = c0 + c1 + c2 + c3;
        int sa = s;
        #pragma unroll
        for (int o = 1; o < 64; o <<= 1) {
            int v = __shfl_up(sa, o);
            if (t >= o) sa += v;
        }
        int e0 = sa - s;                      // exclusive lane base
        int e1 = e0 + c0, e2 = e1 + c1, e3 = e2 + c2;
        lofs[4 * t] = e0; lofs[4 * t + 1] = e1;
        lofs[4 * t + 2] = e2; lofs[4 * t + 3] = e3;
        lcnt[4 * t] = 0; lcnt[4 * t + 1] = 0;
        lcnt[4 * t + 2] = 0; lcnt[4 * t + 3] = 0;
        int n0 = nb0 + 4 * t;
        if (n0 < N)     meta[n0]     = make_int2(pstart + e0, c0);
        if (n0 + 1 < N) meta[n0 + 1] = make_int2(pstart + e1, c1);
        if (n0 + 2 < N) meta[n0 + 2] = make_int2(pstart + e2, c2);
        if (n0 + 3 < N) meta[n0 + 3] = make_int2(pstart + e3, c3);
    }
    __syncthreads();
    // place: direct global write (region is block-exclusive, L2-resident);
    // satom adds the precomputed f16 message
    #pragma unroll
    for (int j = 0; j < 8; ++j) {
        int i = j * 1024 + t;
        if (i < cnt) {
            int2 v = myv[j];
            if (v.x != -1) {
                int ld = ((unsigned)v.x) >> 24;
                int srcid = v.x & 0x00FFFFFF;
                ushort a16 = (ushort)(((unsigned)v.y) >> 16);
                ushort m16 = (ushort)(v.y & 0xFFFF);
                int r = atomicAdd(&lcnt[ld], 1);
                int pos = lofs[ld] + r;
                pairs[pstart + pos] = make_int2(srcid << 7,
                                     __builtin_bit_cast(int, f16bits2f(a16)));
                atomicAdd(&satom[ld], f16bits2f(m16));
            }
        }
    }
    __syncthreads();
    if (t < BNODES) {
        int node = nb0 + t;
        if (node < N) hin0[node] = x[node] + satom[t];
    }
}

// ---- aggregation: wave = 4 nodes x 16 lanes, 16-deep gather pipeline ------

__device__ __forceinline__ void agg_add8(f32x2 acc2[4], uint2 g, float e) {
    f32x2 e2 = {e, e}, z2 = {0.f, 0.f};
    unsigned gw[2] = {g.x, g.y};
    #pragma unroll
    for (int ww = 0; ww < 2; ++ww) {
        f32x2 lo = __builtin_amdgcn_cvt_pk_f32_fp8((int)gw[ww], false);
        f32x2 hi = __builtin_amdgcn_cvt_pk_f32_fp8((int)gw[ww], true);
        lo = __builtin_elementwise_max(lo + e2, z2);
        hi = __builtin_elementwise_max(hi + e2, z2);
        acc2[2 * ww]     += lo;
        acc2[2 * ww + 1] += hi;
    }
}

__device__ __forceinline__ uint2 agg_ld8(const char* __restrict__ hb,
                                         int voff) {
    return *(const uint2*)(hb + (unsigned)voff);
}

__global__ __launch_bounds__(256, 4) void k_agg(
    const unsigned char* __restrict__ h8,
    const f16* __restrict__ hf,
    const int2* __restrict__ pairs,
    const int2* __restrict__ meta,
    f16* __restrict__ oh, int n) {

    int t = threadIdx.x;
    int w = t >> 6, lane = t & 63;
    int g = lane >> 4, c = lane & 15;
    int node = blockIdx.x * 16 + w * 4 + g;
    int c8 = c * 8;
    int sbase = g * 16;
    const char* hb = (const char*)h8;

    int2 m = make_int2(0, 0);
    if (node < n) m = meta[node];
    int off = m.x, d = m.y;
    f32x2 acc2[4] = {{0.f,0.f},{0.f,0.f},{0.f,0.f},{0.f,0.f}};

    for (int wb = 0; wb < d; wb += 16) {
        int rem = d - wb;
        int mm = rem < 16 ? rem : 16;
        int2 pr = make_int2(0, 0);
        if (c < mm) pr = pairs[off + wb + c];
        uint2 gg[16];
        #pragma unroll
        for (int p = 0; p < 16; ++p) {
            int s = __shfl(pr.x, sbase + p);
            if (p < mm) gg[p] = agg_ld8(hb, s + c8);
        }
        #pragma unroll
        for (int p = 0; p < 16; ++p) {
            if (p < mm) {
                float e = bcf(__shfl(pr.y, sbase + p));
                agg_add8(acc2, gg[p], e);
            }
        }
    }

    if (node < n) {
        uint4 sg = *(const uint4*)&hf[(size_t)node * HID + c8];
        unsigned sw[4] = {sg.x, sg.y, sg.z, sg.w};
        unsigned ow[4];
        #pragma unroll
        for (int ww = 0; ww < 4; ++ww) {
            f16x2 s = __builtin_bit_cast(f16x2, sw[ww]);
            f16x2 o;
            o[0] = (f16)((float)s[0] + acc2[ww].x);
            o[1] = (f16)((float)s[1] + acc2[ww].y);
            ow[ww] = __builtin_bit_cast(unsigned, o);
        }
        uint4 o4;
        o4.x = ow[0]; o4.y = ow[1]; o4.z = ow[2]; o4.w = ow[3];
        *(uint4*)&oh[(size_t)node * HID + c8] = o4;
    }
}

// ---- MLP helpers (single-product f16 weights) -----------------------------

__device__ __forceinline__ void load_wfrags1(const f16* __restrict__ Wfg,
                                             int w, int lane,
                                             f16x8 whf[4][2]) {
    #pragma unroll
    for (int kk = 0; kk < 4; ++kk)
        #pragma unroll
        for (int nf = 0; nf < 2; ++nf) {
            size_t o = (((size_t)kk * 2 + nf) * 4 + w) * 512 +
                       (size_t)lane * 8;
            whf[kk][nf] = *(const f16x8*)&Wfg[o];
        }
}

__device__ __forceinline__ void do_gemm1(const f16* Ah,
                                         const f16x8 whf[4][2],
                                         int lane, f32x4 acc[4][2]) {
    int arow = lane & 15, akgrp = lane >> 4;
    #pragma unroll
    for (int kk = 0; kk < 4; ++kk) {
        int chunk = kk * 4 + akgrp;
        f16x8 ah[4];
        #pragma unroll
        for (int mf = 0; mf < 4; ++mf) {
            int r = mf * 16 + arow;
            int swz = chunk ^ (r & 15);
            ah[mf] = *(const f16x8*)&Ah[r * HID + swz * 8];
        }
        #pragma unroll
        for (int mf = 0; mf < 4; ++mf)
            #pragma unroll
            for (int nf = 0; nf < 2; ++nf)
                acc[mf][nf] = __builtin_amdgcn_mfma_f32_16x16x32_f16(
                    ah[mf], whf[kk][nf], acc[mf][nf], 0, 0, 0);
    }
}

// vectorized output: acc -> swizzled LDS -> f16x8 + packed-fp8 stores.
// Caller must barrier AFTER do_gemm1 (A reads done) before calling.
__device__ __forceinline__ void store_out_vec(
    f16* __restrict__ bufA, const f32x4 acc[4][2],
    float bv0, float bv1,
    int t, int wcol, int fcol, int kgrp, int row0,
    f16* __restrict__ O, unsigned char* __restrict__ O8, int w8, int n) {

    #pragma unroll
    for (int mf = 0; mf < 4; ++mf)
        #pragma unroll
        for (int nf = 0; nf < 2; ++nf) {
            int cc = wcol + nf * 16 + fcol;
            float bb = nf ? bv1 : bv0;
            #pragma unroll
            for (int j = 0; j < 4; ++j) {
                int r = mf * 16 + kgrp * 4 + j;
                float v = fmaxf(acc[mf][nf][j] + bb, 0.f);
                int addr = r * HID + (((cc >> 3) ^ (r & 15)) << 3) + (cc & 7);
                bufA[addr] = (f16)v;
            }
        }
    __syncthreads();
    #pragma unroll
    for (int rep = 0; rep < 4; ++rep) {
        int task = rep * 256 + t;
        int r = task >> 4, ch = task & 15;
        int gr = row0 + r;
        if (gr < n) {
            int swz = ch ^ (r & 15);
            f16x8 hv = *(const f16x8*)&bufA[r * HID + swz * 8];
            *(f16x8*)&O[(size_t)gr * HID + ch * 8] = hv;
            if (w8) {
                int pk0 = __builtin_amdgcn_cvt_pk_fp8_f32(
                    (float)hv[0], (float)hv[1], 0, false);
                pk0 = __builtin_amdgcn_cvt_pk_fp8_f32(
                    (float)hv[2], (float)hv[3], pk0, true);
                int pk1 = __builtin_amdgcn_cvt_pk_fp8_f32(
                    (float)hv[4], (float)hv[5], 0, false);
                pk1 = __builtin_amdgcn_cvt_pk_fp8_f32(
                    (float)hv[6], (float)hv[7], pk1, true);
                uint2 o8v = make_uint2((unsigned)pk0, (unsigned)pk1);
                *(uint2*)&O8[(size_t)gr * HID + ch * 8] = o8v;
            }
        }
    }
}

// ---- MLP: O = relu(relu(A@W1+b1)@W2+b2), A f16 plane; fp8 shadow write ----

__global__ __launch_bounds__(256, 3) void k_mlp(
    const f16* __restrict__ A_g,
    const f16* __restrict__ Wf1, const float* __restrict__ b1,
    const f16* __restrict__ Wf2, const float* __restrict__ b2,
    f16* __restrict__ O, unsigned char* __restrict__ O8, int w8, int n) {

    __shared__ __align__(16) f16 bufA[64 * HID];   // A, then T, then out
    int t = threadIdx.x, w = t >> 6, lane = t & 63;
    int wcol = w * 32, fcol = lane & 15, kgrp = lane >> 4;
    int row0 = blockIdx.x * 64;

    #pragma unroll
    for (int rep = 0; rep < 4; ++rep) {
        int task = rep * 256 + t;
        int r = task >> 4, ch = task & 15;
        int gr = min(row0 + r, n - 1);
        int swz = ch ^ (r & 15);
        *(f16x8*)&bufA[r * HID + swz * 8] =
            *(const f16x8*)&A_g[(size_t)gr * HID + ch * 8];
    }

    f32x4 acc[4][2];
    {
        f16x8 whf[4][2];
        load_wfrags1(Wf1, w, lane, whf);
        float bv0 = b1[wcol + fcol], bv1 = b1[wcol + 16 + fcol];
        __syncthreads();
        #pragma unroll
        for (int mf = 0; mf < 4; ++mf)
            #pragma unroll
            for (int nf = 0; nf < 2; ++nf)
                acc[mf][nf] = (f32x4)(0.f);
        do_gemm1(bufA, whf, lane, acc);
        __syncthreads();   // all A reads done before T overwrites
        #pragma unroll
        for (int mf = 0; mf < 4; ++mf)
            #pragma unroll
            for (int nf = 0; nf < 2; ++nf) {
                int cc = wcol + nf * 16 + fcol;
                float bb = nf ? bv1 : bv0;
                #pragma unroll
                for (int j = 0; j < 4; ++j) {
                    int r = mf * 16 + kgrp * 4 + j;
                    float v = fmaxf(acc[mf][nf][j] + bb, 0.f);
                    int addr = r * HID + (((cc >> 3) ^ (r & 15)) << 3) + (cc & 7);
                    bufA[addr] = (f16)v;
                }
            }
    }
    {
        f16x8 whf[4][2];
        load_wfrags1(Wf2, w, lane, whf);
        float bv0 = b2[wcol + fcol], bv1 = b2[wcol + 16 + fcol];
        __syncthreads();
        #pragma unroll
        for (int mf = 0; mf < 4; ++mf)
            #pragma unroll
            for (int nf = 0; nf < 2; ++nf)
                acc[mf][nf] = (f32x4)(0.f);
        do_gemm1(bufA, whf, lane, acc);
        __syncthreads();   // all T reads done before outputs overwrite
        store_out_vec(bufA, acc, bv0, bv1, t, wcol, fcol, kgrp, row0,
                      O, O8, w8, n);
    }
}

// ---- layer-0 MLP (rank-1 expansion fused) ---------------------------------

__global__ __launch_bounds__(256, 3) void k_mlp0(
    const float* __restrict__ r1x, const float* __restrict__ r1w,
    const float* __restrict__ r1b,
    const f16* __restrict__ Wf2, const float* __restrict__ b2,
    f16* __restrict__ O, unsigned char* __restrict__ O8, int n) {

    __shared__ __align__(16) f16 bufA[64 * HID];
    int t = threadIdx.x, w = t >> 6, lane = t & 63;
    int wcol = w * 32, fcol = lane & 15, kgrp = lane >> 4;
    int row0 = blockIdx.x * 64;

    #pragma unroll
    for (int rep = 0; rep < 4; ++rep) {
        int task = rep * 256 + t;
        int r = task >> 4, ch = task & 15;
        int gr = min(row0 + r, n - 1);
        int swz = ch ^ (r & 15);
        float xv = r1x[gr];
        f16x8 hi;
        #pragma unroll
        for (int j = 0; j < 8; ++j)
            hi[j] = (f16)fmaxf(xv * r1w[ch * 8 + j] + r1b[ch * 8 + j], 0.f);
        *(f16x8*)&bufA[r * HID + swz * 8] = hi;
    }

    f16x8 whf[4][2];
    load_wfrags1(Wf2, w, lane, whf);
    float bv0 = b2[wcol + fcol], bv1 = b2[wcol + 16 + fcol];
    __syncthreads();
    f32x4 acc[4][2];
    #pragma unroll
    for (int mf = 0; mf < 4; ++mf)
        #pragma unroll
        for (int nf = 0; nf < 2; ++nf)
            acc[mf][nf] = (f32x4)(0.f);
    do_gemm1(bufA, whf, lane, acc);
    __syncthreads();   // all A reads done before outputs overwrite
    store_out_vec(bufA, acc, bv0, bv1, t, wcol, fcol, kgrp, row0,
                  O, O8, 1, n);
}

// ---- mean pool + head: 256 threads, 4 rows in flight, f16x2 loads ---------

__global__ __launch_bounds__(256) void k_head(const f16* __restrict__ h,
                                              const int* __restrict__ gstart,
                                              const int* __restrict__ gcount,
                                              const float* __restrict__ Wc,
                                              const float* __restrict__ bc,
                                              float* __restrict__ out, int G) {
    __shared__ float2 red[4][64];
    __shared__ float pl[HID];
    int g = blockIdx.x, t = threadIdx.x;
    int rr = t >> 6, cc = t & 63;
    int st = gstart[g], c = gcount[g];
    float2 acc = make_float2(0.f, 0.f);
    for (int i = rr; i < c; i += 4) {
        unsigned u = *(const unsigned*)&h[(size_t)(st + i) * HID + cc * 2];
        f16x2 v = __builtin_bit_cast(f16x2, u);
        acc.x += (float)v[0];
        acc.y += (float)v[1];
    }
    red[rr][cc] = acc;
    __syncthreads();
    if (rr == 0) {
        #pragma unroll
        for (int k = 1; k < 4; ++k) {
            acc.x += red[k][cc].x;
            acc.y += red[k][cc].y;
        }
        float inv = 1.f / fmaxf((float)c, 1.f);
        pl[cc * 2]     = acc.x * inv;
        pl[cc * 2 + 1] = acc.y * inv;
    }
    __syncthreads();
    if (t < NCLS) {
        float o = bc[t];
        for (int k = 0; k < HID; ++k) o += pl[k] * Wc[k * NCLS + t];
        out[g * NCLS + t] = o;
    }
}

// ---------------------------------------------------------------------------

static inline size_t alignup(size_t x, size_t a) { return (x + a - 1) & ~(a - 1); }

extern "C" void kernel_launch(void* const* d_in, const int* in_sizes, int n_in,
                              void* d_out, int out_size, void* d_ws, size_t ws_size,
                              hipStream_t stream) {
    const float* x      = (const float*)d_in[0];
    const int*   ei     = (const int*)d_in[1];
    const float* eattr  = (const float*)d_in[2];
    const int*   batch  = (const int*)d_in[3];
    const float* W1_0   = (const float*)d_in[4];
    const float* b1_0   = (const float*)d_in[5];
    const float* W2_0   = (const float*)d_in[6];
    const float* b2_0   = (const float*)d_in[7];
    const float* W1_s   = (const float*)d_in[8];
    const float* b1_s   = (const float*)d_in[9];
    const float* W2_s   = (const float*)d_in[10];
    const float* b2_s   = (const float*)d_in[11];
    const float* Wc     = (const float*)d_in[12];
    const float* bc     = (const float*)d_in[13];

    const int N = in_sizes[0];          // 100000
    const int E = in_sizes[2];          // 1600000
    const int G = out_size / NCLS;      // 1000
    const int* srcI = ei;
    const int* dstI = ei + E;

    const int NB = (N + BNODES - 1) >> BSHIFT;          // 391 buckets
    const int NBLK = (E + EPB - 1) / EPB;               // 782 binning blocks
    const int GSB = (N + 1023) / 1024;                  // 98 gseg blocks

    char* p = (char*)d_ws;
    size_t off = 0;
    size_t gcount_off = off;         off = alignup(off + (size_t)G * 4, 256);
    size_t gstart_off = off;         off = alignup(off + (size_t)G * 4, 256);
    size_t cursor_off = off;         off = alignup(off + 512 * 4, 256);
    size_t zero_bytes = off;
    size_t meta_off = off;           off = alignup(off + (size_t)N * 8, 256);
    size_t bbase_off = off;          off = alignup(off + 513 * 4, 256);
    size_t hin0_off = off;           off = alignup(off + (size_t)N * 4, 256);
    size_t wf_off = off;             off = alignup(off + 7 * 16384 * 2, 256);
    size_t pairs_off = off;          off = alignup(off + (size_t)NB * ECAP * 8, 256);
    size_t p0_off = off;             off = alignup(off + (size_t)N * HID * 2, 256);
    size_t p8_off = off;             off = alignup(off + (size_t)N * HID, 256);
    size_t p1_off = off;             off = alignup(off + (size_t)N * HID * 2, 256);

    int*    gcount  = (int*)(p + gcount_off);
    int*    gstart  = (int*)(p + gstart_off);
    int*    cursor  = (int*)(p + cursor_off);
    int2*   meta    = (int2*)(p + meta_off);
    int*    bbase   = (int*)(p + bbase_off);
    float*  hin0    = (float*)(p + hin0_off);
    f16*    Wf      = (f16*)(p + wf_off);
    int2*   pairs   = (int2*)(p + pairs_off);
    f16*    P0      = (f16*)(p + p0_off);
    unsigned char* P8 = (unsigned char*)(p + p8_off);
    f16*    P1      = (f16*)(p + p1_off);
    // ebuf aliases P1 (dead until layer-1's k_agg writes P1):
    // NB*ECAP*8B = 391*7500*8 = 23.46MB <= N*HID*2B = 25.6MB
    int2*   ebuf    = (int2*)(p + p1_off);

    hipMemsetAsync(d_ws, 0, zero_bytes, stream);

    int gblk = (N + 63) / 64;
    int abl = (N + 15) / 16;            // k_agg: 16 nodes per 256-thr block

    k_bin2<<<NBLK, 1024, 0, stream>>>(srcI, dstI, eattr, x, cursor, ebuf,
                                      E, NB);
    k_prep<<<15 + GSB, 1024, 0, stream>>>(W2_0, W1_s, W2_s, Wf, cursor,
                                          bbase, batch, gcount, gstart,
                                          NB, N);
    k_fill2<<<NB, 1024, 0, stream>>>(ebuf, cursor, bbase, x, meta,
                                     pairs, hin0, N);

    // Wf plane bases: g=0 -> W2_0; g=1+2l -> W1_s[l]; g=2+2l -> W2_s[l]
    #define WFG(g) (Wf + (size_t)(g) * 16384)

    // layer 0: rank1-expand + GEMM(W2_0) -> P0 (f16 + fp8 shadow)
    k_mlp0<<<gblk, 256, 0, stream>>>(hin0, W1_0, b1_0, WFG(0), b2_0,
                                     P0, P8, N);

    // layers 1..3: agg (P8 gather, P0 self -> P1) + MLP (P1 -> P0 [+P8])
    for (int l = 0; l < 3; ++l) {
        const float* b1 = b1_s + (size_t)l * HID;
        const float* b2 = b2_s + (size_t)l * HID;
        k_agg<<<abl, 256, 0, stream>>>(P8, P0, pairs, meta, P1, N);
        k_mlp<<<gblk, 256, 0, stream>>>(P1, WFG(1 + 2 * l), b1,
                                        WFG(2 + 2 * l), b2, P0, P8,
                                        (l < 2) ? 1 : 0, N);
    }

    k_head<<<G, 256, 0, stream>>>(P0, gstart, gcount, Wc, bc,
                                  (float*)d_out, G);
}

// Round 15
// 264.039 us; speedup vs baseline: 1.0763x; 1.0763x over previous
//
#include <hip/hip_runtime.h>
#include <hip/hip_bf16.h>

// ---------------------------------------------------------------------------
// GINE GNN. Features: f16 plane (self/MLP) + fp8-e4m3 shadow plane gathered
// by k_agg (r8 layout: wave = 4 nodes x 16 lanes, 16-deep gather pipeline).
// CSR: single-pass bucket binning (256-node buckets, line-aligned
// reservations, EPB 4096 = r13's proven optimum; r14 showed more blocks
// regress) + per-bucket sort (512 thr) with register staging + direct pairs
// writes. r15: W-prefragmentation and graph-segment prep (both independent
// of binning) merged as role-blocks into k_bin2m's grid -- they hide under
// the latency-bound binning blocks; only the cursor scan (k_scan, 1 block)
// stays serial. MLP epilogues vectorized via swizzled-LDS -> f16x8 +
// packed-fp8 (r13). Lessons: r2/r11 = cross-XCD fine-grain scatter/atomics
// in hot per-edge paths kill; r4 = never trade reg accumulation for LDS
// atomics; r8 = gather MLP depth is the agg lever; r9 = agg+MLP fusion
// net-neutral; r10/r12 = line-dense reservations + all-CU grids fixed bin2;
// r13 = vector epilogues (-23us); r14 = block-TLP saturated at EPB 4096.
// ---------------------------------------------------------------------------

#define HID 128
#define NCLS 3
#define EPB 4096          // edges per binning block (391 blocks, all CUs)
#define BSHIFT 8          // bucket = dst >> 8 (256 nodes/bucket)
#define BNODES 256
#define ECAP 6400         // slots per bucket (mean padded ~5490, +11 sigma)

typedef _Float16 f16;
typedef f16 f16x2 __attribute__((ext_vector_type(2)));
typedef f16 f16x8 __attribute__((ext_vector_type(8)));
typedef float f32x2 __attribute__((ext_vector_type(2)));
typedef float f32x4 __attribute__((ext_vector_type(4)));
typedef unsigned short ushort;

__device__ __forceinline__ float bcf(int v) {
    return __builtin_bit_cast(float, v);
}
__device__ __forceinline__ float f16bits2f(ushort u) {
    return (float)__builtin_bit_cast(f16, u);
}

// ---- merged: binning + W prefrag + graph-segment prep (role-blocks) -------
// blocks [0,NBLK): CSR binning -- ONE pass count+reserve(line-aligned)+place
//   ebuf slot: x = src | (dstlocal<<24), y = (attr_f16<<16) | msg0_f16
// blocks [NBLK,NBLK+14): W prefragmentation (f16 per-lane MFMA layout)
// blocks [NBLK+14,...): graph-segment prep (gcount/gstart from batch)

__global__ __launch_bounds__(1024) void k_bin2m(
    const int* __restrict__ src, const int* __restrict__ dst,
    const float* __restrict__ eattr, const float* __restrict__ x,
    int* __restrict__ cursor, int2* __restrict__ ebuf,
    const float* __restrict__ W2_0, const float* __restrict__ W1_s,
    const float* __restrict__ W2_s, f16* __restrict__ Wf,
    const int* __restrict__ batch, int* __restrict__ gcount,
    int* __restrict__ gstart,
    int E, int NB, int NBLK, int N) {

    __shared__ int lh[512];
    __shared__ int lbase[512];
    __shared__ int lrsv[512];
    int t = threadIdx.x;

    if (blockIdx.x < (unsigned)NBLK) {
        // ---------------- binning role ----------------
        if (t < NB) lh[t] = 0;
        __syncthreads();
        int base = blockIdx.x * EPB;
        int myd[4];
        #pragma unroll
        for (int j = 0; j < 4; ++j) {
            int e = base + j * 1024 + t;
            myd[j] = (e < E) ? dst[e] : -1;
            if (myd[j] >= 0) atomicAdd(&lh[myd[j] >> BSHIFT], 1);
        }
        __syncthreads();
        if (t < NB) {
            int c = lh[t];
            int cp = (c + 7) & ~7;           // 64B-line-aligned reservation
            lrsv[t] = cp;
            lbase[t] = (cp > 0) ? (t * ECAP + atomicAdd(&cursor[t], cp)) : 0;
            lh[t] = 0;
        }
        __syncthreads();
        #pragma unroll
        for (int j = 0; j < 4; ++j) {
            if (myd[j] >= 0) {
                int e = base + j * 1024 + t;
                int b = myd[j] >> BSHIFT;
                int s = src[e];
                float at = eattr[e];
                float msg = fmaxf(x[s] + at, 0.f);   // layer-0 message
                unsigned a16 = __builtin_bit_cast(ushort, (f16)at);
                unsigned m16 = __builtin_bit_cast(ushort, (f16)msg);
                int r = atomicAdd(&lh[b], 1);
                int pos = lbase[b] + r;
                if (pos < (b + 1) * ECAP)      // overflow guard (never hits)
                    ebuf[pos] = make_int2(s | ((myd[j] & (BNODES - 1)) << 24),
                                          (int)((a16 << 16) | m16));
            }
        }
        __syncthreads();
        // sentinel-fill this block's padding (<=7 per bucket, own lines)
        if (t < NB) {
            int c = lh[t], cp = lrsv[t];
            int p0 = lbase[t] + c;
            int pe = lbase[t] + cp;
            int cap = (t + 1) * ECAP;
            if (pe > cap) pe = cap;
            for (int pos = p0; pos < pe; ++pos)
                ebuf[pos] = make_int2(-1, 0);
        }
    } else if (blockIdx.x < (unsigned)(NBLK + 14)) {
        // ---------------- W prefragmentation role ----------------
        int id = (blockIdx.x - NBLK) * 1024 + t;     // [0, 14336)
        int lane = id & 63;
        int w    = (id >> 6) & 3;
        int nf   = (id >> 8) & 1;
        int kk   = (id >> 9) & 3;
        int g    = id >> 11;
        const float* W = (g == 0) ? W2_0
                       : ((g & 1) ? W1_s + (size_t)((g - 1) >> 1) * HID * HID
                                  : W2_s + (size_t)((g - 2) >> 1) * HID * HID);
        int col = w * 32 + nf * 16 + (lane & 15);
        int k0  = kk * 32 + (lane >> 4) * 8;
        f16x8 hi;
        #pragma unroll
        for (int j = 0; j < 8; ++j)
            hi[j] = (f16)W[(k0 + j) * HID + col];
        size_t o = ((((size_t)g * 4 + kk) * 2 + nf) * 4 + w) * 512 +
                   (size_t)lane * 8;
        *(f16x8*)&Wf[o] = hi;
    } else {
        // ---------------- graph-segment role ----------------
        int i = (blockIdx.x - NBLK - 14) * 1024 + t;
        if (i < N) {
            int gb = batch[i];
            atomicAdd(&gcount[gb], 1);
            if (i == 0 || batch[i - 1] != gb) gstart[gb] = i;
        }
    }
}

// ---- scan of bucket totals (depends on cursor; 1 block) -------------------

__global__ __launch_bounds__(1024) void k_scan(const int* __restrict__ cursor,
                                               int* __restrict__ bbase,
                                               int NB) {
    __shared__ int sd[1024];
    int t = threadIdx.x;
    int v = (t < NB) ? min(cursor[t], ECAP) : 0;
    sd[t] = v;
    __syncthreads();
    #pragma unroll
    for (int o = 1; o < 1024; o <<= 1) {
        int add = (t >= o) ? sd[t - o] : 0;
        __syncthreads();
        sd[t] += add;
        __syncthreads();
    }
    if (t < NB) bbase[t] = sd[t] - v;
    if (t == 1023) bbase[NB] = sd[1023];
}

// per-bucket (256 nodes): global read into REGISTERS (<=13 slots per thread,
// statically unrolled); skip sentinels; count via LDS atomics; scan of 256
// counters by wave 0 via shfl (4 counters/lane); place DIRECTLY to global
// pairs (block-exclusive region -> L2-absorbed, written back once).
// pairs.x = src*128 byte offset (fp8 plane); pairs.y = f32 attr bits.
__global__ __launch_bounds__(512, 8) void k_fill2(const int2* __restrict__ ebuf,
                                               const int* __restrict__ btot,
                                               const int* __restrict__ bbase,
                                               const float* __restrict__ x,
                                               int2* __restrict__ meta,
                                               int2* __restrict__ pairs,
                                               float* __restrict__ hin0,
                                               int N) {
    __shared__ int lcnt[BNODES];
    __shared__ int lofs[BNODES];
    __shared__ float satom[BNODES];
    int b = blockIdx.x, t = threadIdx.x;
    int estart = b * ECAP;
    int cnt = min(btot[b], ECAP);
    int pstart = bbase[b];
    int nb0 = b << BSHIFT;
    if (t < BNODES) {
        lcnt[t] = 0;
        satom[t] = 0.f;
    }
    __syncthreads();
    // load slots into registers: 13 independent loads in flight, then count
    int2 myv[13];
    #pragma unroll
    for (int j = 0; j < 13; ++j) {
        int i = j * 512 + t;
        if (i < cnt) myv[j] = ebuf[estart + i];
    }
    #pragma unroll
    for (int j = 0; j < 13; ++j) {
        int i = j * 512 + t;
        if (i < cnt && myv[j].x != -1)
            atomicAdd(&lcnt[((unsigned)myv[j].x) >> 24], 1);
    }
    __syncthreads();
    // wave 0 scans the 256 counters via shfl (4 counters/lane)
    if (t < 64) {
        int c0 = lcnt[4 * t], c1 = lcnt[4 * t + 1];
        int c2 = lcnt[4 * t + 2], c3 = lcnt[4 * t + 3];
        int s = c0 + c1 + c2 + c3;
        int sa = s;
        #pragma unroll
        for (int o = 1; o < 64; o <<= 1) {
            int v = __shfl_up(sa, o);
            if (t >= o) sa += v;
        }
        int e0 = sa - s;                      // exclusive lane base
        int e1 = e0 + c0, e2 = e1 + c1, e3 = e2 + c2;
        lofs[4 * t] = e0; lofs[4 * t + 1] = e1;
        lofs[4 * t + 2] = e2; lofs[4 * t + 3] = e3;
        lcnt[4 * t] = 0; lcnt[4 * t + 1] = 0;
        lcnt[4 * t + 2] = 0; lcnt[4 * t + 3] = 0;
        int n0 = nb0 + 4 * t;
        if (n0 < N)     meta[n0]     = make_int2(pstart + e0, c0);
        if (n0 + 1 < N) meta[n0 + 1] = make_int2(pstart + e1, c1);
        if (n0 + 2 < N) meta[n0 + 2] = make_int2(pstart + e2, c2);
        if (n0 + 3 < N) meta[n0 + 3] = make_int2(pstart + e3, c3);
    }
    __syncthreads();
    // place: direct global write (region is block-exclusive, L2-resident);
    // satom adds the precomputed f16 message
    #pragma unroll
    for (int j = 0; j < 13; ++j) {
        int i = j * 512 + t;
        if (i < cnt) {
            int2 v = myv[j];
            if (v.x != -1) {
                int ld = ((unsigned)v.x) >> 24;
                int srcid = v.x & 0x00FFFFFF;
                ushort a16 = (ushort)(((unsigned)v.y) >> 16);
                ushort m16 = (ushort)(v.y & 0xFFFF);
                int r = atomicAdd(&lcnt[ld], 1);
                int pos = lofs[ld] + r;
                pairs[pstart + pos] = make_int2(srcid << 7,
                                     __builtin_bit_cast(int, f16bits2f(a16)));
                atomicAdd(&satom[ld], f16bits2f(m16));
            }
        }
    }
    __syncthreads();
    if (t < BNODES) {
        int node = nb0 + t;
        if (node < N) hin0[node] = x[node] + satom[t];
    }
}

// ---- aggregation: wave = 4 nodes x 16 lanes, 16-deep gather pipeline ------

__device__ __forceinline__ void agg_add8(f32x2 acc2[4], uint2 g, float e) {
    f32x2 e2 = {e, e}, z2 = {0.f, 0.f};
    unsigned gw[2] = {g.x, g.y};
    #pragma unroll
    for (int ww = 0; ww < 2; ++ww) {
        f32x2 lo = __builtin_amdgcn_cvt_pk_f32_fp8((int)gw[ww], false);
        f32x2 hi = __builtin_amdgcn_cvt_pk_f32_fp8((int)gw[ww], true);
        lo = __builtin_elementwise_max(lo + e2, z2);
        hi = __builtin_elementwise_max(hi + e2, z2);
        acc2[2 * ww]     += lo;
        acc2[2 * ww + 1] += hi;
    }
}

__device__ __forceinline__ uint2 agg_ld8(const char* __restrict__ hb,
                                         int voff) {
    return *(const uint2*)(hb + (unsigned)voff);
}

__global__ __launch_bounds__(256, 4) void k_agg(
    const unsigned char* __restrict__ h8,
    const f16* __restrict__ hf,
    const int2* __restrict__ pairs,
    const int2* __restrict__ meta,
    f16* __restrict__ oh, int n) {

    int t = threadIdx.x;
    int w = t >> 6, lane = t & 63;
    int g = lane >> 4, c = lane & 15;
    int node = blockIdx.x * 16 + w * 4 + g;
    int c8 = c * 8;
    int sbase = g * 16;
    const char* hb = (const char*)h8;

    int2 m = make_int2(0, 0);
    if (node < n) m = meta[node];
    int off = m.x, d = m.y;
    f32x2 acc2[4] = {{0.f,0.f},{0.f,0.f},{0.f,0.f},{0.f,0.f}};

    for (int wb = 0; wb < d; wb += 16) {
        int rem = d - wb;
        int mm = rem < 16 ? rem : 16;
        int2 pr = make_int2(0, 0);
        if (c < mm) pr = pairs[off + wb + c];
        uint2 gg[16];
        #pragma unroll
        for (int p = 0; p < 16; ++p) {
            int s = __shfl(pr.x, sbase + p);
            if (p < mm) gg[p] = agg_ld8(hb, s + c8);
        }
        #pragma unroll
        for (int p = 0; p < 16; ++p) {
            if (p < mm) {
                float e = bcf(__shfl(pr.y, sbase + p));
                agg_add8(acc2, gg[p], e);
            }
        }
    }

    if (node < n) {
        uint4 sg = *(const uint4*)&hf[(size_t)node * HID + c8];
        unsigned sw[4] = {sg.x, sg.y, sg.z, sg.w};
        unsigned ow[4];
        #pragma unroll
        for (int ww = 0; ww < 4; ++ww) {
            f16x2 s = __builtin_bit_cast(f16x2, sw[ww]);
            f16x2 o;
            o[0] = (f16)((float)s[0] + acc2[ww].x);
            o[1] = (f16)((float)s[1] + acc2[ww].y);
            ow[ww] = __builtin_bit_cast(unsigned, o);
        }
        uint4 o4;
        o4.x = ow[0]; o4.y = ow[1]; o4.z = ow[2]; o4.w = ow[3];
        *(uint4*)&oh[(size_t)node * HID + c8] = o4;
    }
}

// ---- MLP helpers (single-product f16 weights) -----------------------------

__device__ __forceinline__ void load_wfrags1(const f16* __restrict__ Wfg,
                                             int w, int lane,
                                             f16x8 whf[4][2]) {
    #pragma unroll
    for (int kk = 0; kk < 4; ++kk)
        #pragma unroll
        for (int nf = 0; nf < 2; ++nf) {
            size_t o = (((size_t)kk * 2 + nf) * 4 + w) * 512 +
                       (size_t)lane * 8;
            whf[kk][nf] = *(const f16x8*)&Wfg[o];
        }
}

__device__ __forceinline__ void do_gemm1(const f16* Ah,
                                         const f16x8 whf[4][2],
                                         int lane, f32x4 acc[4][2]) {
    int arow = lane & 15, akgrp = lane >> 4;
    #pragma unroll
    for (int kk = 0; kk < 4; ++kk) {
        int chunk = kk * 4 + akgrp;
        f16x8 ah[4];
        #pragma unroll
        for (int mf = 0; mf < 4; ++mf) {
            int r = mf * 16 + arow;
            int swz = chunk ^ (r & 15);
            ah[mf] = *(const f16x8*)&Ah[r * HID + swz * 8];
        }
        #pragma unroll
        for (int mf = 0; mf < 4; ++mf)
            #pragma unroll
            for (int nf = 0; nf < 2; ++nf)
                acc[mf][nf] = __builtin_amdgcn_mfma_f32_16x16x32_f16(
                    ah[mf], whf[kk][nf], acc[mf][nf], 0, 0, 0);
    }
}

// vectorized output: acc -> swizzled LDS -> f16x8 + packed-fp8 stores.
// Caller must barrier AFTER do_gemm1 (A reads done) before calling.
__device__ __forceinline__ void store_out_vec(
    f16* __restrict__ bufA, const f32x4 acc[4][2],
    float bv0, float bv1,
    int t, int wcol, int fcol, int kgrp, int row0,
    f16* __restrict__ O, unsigned char* __restrict__ O8, int w8, int n) {

    #pragma unroll
    for (int mf = 0; mf < 4; ++mf)
        #pragma unroll
        for (int nf = 0; nf < 2; ++nf) {
            int cc = wcol + nf * 16 + fcol;
            float bb = nf ? bv1 : bv0;
            #pragma unroll
            for (int j = 0; j < 4; ++j) {
                int r = mf * 16 + kgrp * 4 + j;
                float v = fmaxf(acc[mf][nf][j] + bb, 0.f);
                int addr = r * HID + (((cc >> 3) ^ (r & 15)) << 3) + (cc & 7);
                bufA[addr] = (f16)v;
            }
        }
    __syncthreads();
    #pragma unroll
    for (int rep = 0; rep < 4; ++rep) {
        int task = rep * 256 + t;
        int r = task >> 4, ch = task & 15;
        int gr = row0 + r;
        if (gr < n) {
            int swz = ch ^ (r & 15);
            f16x8 hv = *(const f16x8*)&bufA[r * HID + swz * 8];
            *(f16x8*)&O[(size_t)gr * HID + ch * 8] = hv;
            if (w8) {
                int pk0 = __builtin_amdgcn_cvt_pk_fp8_f32(
                    (float)hv[0], (float)hv[1], 0, false);
                pk0 = __builtin_amdgcn_cvt_pk_fp8_f32(
                    (float)hv[2], (float)hv[3], pk0, true);
                int pk1 = __builtin_amdgcn_cvt_pk_fp8_f32(
                    (float)hv[4], (float)hv[5], 0, false);
                pk1 = __builtin_amdgcn_cvt_pk_fp8_f32(
                    (float)hv[6], (float)hv[7], pk1, true);
                uint2 o8v = make_uint2((unsigned)pk0, (unsigned)pk1);
                *(uint2*)&O8[(size_t)gr * HID + ch * 8] = o8v;
            }
        }
    }
}

// ---- MLP: O = relu(relu(A@W1+b1)@W2+b2), A f16 plane; fp8 shadow write ----

__global__ __launch_bounds__(256, 3) void k_mlp(
    const f16* __restrict__ A_g,
    const f16* __restrict__ Wf1, const float* __restrict__ b1,
    const f16* __restrict__ Wf2, const float* __restrict__ b2,
    f16* __restrict__ O, unsigned char* __restrict__ O8, int w8, int n) {

    __shared__ __align__(16) f16 bufA[64 * HID];   // A, then T, then out
    int t = threadIdx.x, w = t >> 6, lane = t & 63;
    int wcol = w * 32, fcol = lane & 15, kgrp = lane >> 4;
    int row0 = blockIdx.x * 64;

    #pragma unroll
    for (int rep = 0; rep < 4; ++rep) {
        int task = rep * 256 + t;
        int r = task >> 4, ch = task & 15;
        int gr = min(row0 + r, n - 1);
        int swz = ch ^ (r & 15);
        *(f16x8*)&bufA[r * HID + swz * 8] =
            *(const f16x8*)&A_g[(size_t)gr * HID + ch * 8];
    }

    f32x4 acc[4][2];
    {
        f16x8 whf[4][2];
        load_wfrags1(Wf1, w, lane, whf);
        float bv0 = b1[wcol + fcol], bv1 = b1[wcol + 16 + fcol];
        __syncthreads();
        #pragma unroll
        for (int mf = 0; mf < 4; ++mf)
            #pragma unroll
            for (int nf = 0; nf < 2; ++nf)
                acc[mf][nf] = (f32x4)(0.f);
        do_gemm1(bufA, whf, lane, acc);
        __syncthreads();   // all A reads done before T overwrites
        #pragma unroll
        for (int mf = 0; mf < 4; ++mf)
            #pragma unroll
            for (int nf = 0; nf < 2; ++nf) {
                int cc = wcol + nf * 16 + fcol;
                float bb = nf ? bv1 : bv0;
                #pragma unroll
                for (int j = 0; j < 4; ++j) {
                    int r = mf * 16 + kgrp * 4 + j;
                    float v = fmaxf(acc[mf][nf][j] + bb, 0.f);
                    int addr = r * HID + (((cc >> 3) ^ (r & 15)) << 3) + (cc & 7);
                    bufA[addr] = (f16)v;
                }
            }
    }
    {
        f16x8 whf[4][2];
        load_wfrags1(Wf2, w, lane, whf);
        float bv0 = b2[wcol + fcol], bv1 = b2[wcol + 16 + fcol];
        __syncthreads();
        #pragma unroll
        for (int mf = 0; mf < 4; ++mf)
            #pragma unroll
            for (int nf = 0; nf < 2; ++nf)
                acc[mf][nf] = (f32x4)(0.f);
        do_gemm1(bufA, whf, lane, acc);
        __syncthreads();   // all T reads done before outputs overwrite
        store_out_vec(bufA, acc, bv0, bv1, t, wcol, fcol, kgrp, row0,
                      O, O8, w8, n);
    }
}

// ---- layer-0 MLP (rank-1 expansion fused) ---------------------------------

__global__ __launch_bounds__(256, 3) void k_mlp0(
    const float* __restrict__ r1x, const float* __restrict__ r1w,
    const float* __restrict__ r1b,
    const f16* __restrict__ Wf2, const float* __restrict__ b2,
    f16* __restrict__ O, unsigned char* __restrict__ O8, int n) {

    __shared__ __align__(16) f16 bufA[64 * HID];
    int t = threadIdx.x, w = t >> 6, lane = t & 63;
    int wcol = w * 32, fcol = lane & 15, kgrp = lane >> 4;
    int row0 = blockIdx.x * 64;

    #pragma unroll
    for (int rep = 0; rep < 4; ++rep) {
        int task = rep * 256 + t;
        int r = task >> 4, ch = task & 15;
        int gr = min(row0 + r, n - 1);
        int swz = ch ^ (r & 15);
        float xv = r1x[gr];
        f16x8 hi;
        #pragma unroll
        for (int j = 0; j < 8; ++j)
            hi[j] = (f16)fmaxf(xv * r1w[ch * 8 + j] + r1b[ch * 8 + j], 0.f);
        *(f16x8*)&bufA[r * HID + swz * 8] = hi;
    }

    f16x8 whf[4][2];
    load_wfrags1(Wf2, w, lane, whf);
    float bv0 = b2[wcol + fcol], bv1 = b2[wcol + 16 + fcol];
    __syncthreads();
    f32x4 acc[4][2];
    #pragma unroll
    for (int mf = 0; mf < 4; ++mf)
        #pragma unroll
        for (int nf = 0; nf < 2; ++nf)
            acc[mf][nf] = (f32x4)(0.f);
    do_gemm1(bufA, whf, lane, acc);
    __syncthreads();   // all A reads done before outputs overwrite
    store_out_vec(bufA, acc, bv0, bv1, t, wcol, fcol, kgrp, row0,
                  O, O8, 1, n);
}

// ---- mean pool + head: 256 threads, 4 rows in flight, f16x2 loads ---------

__global__ __launch_bounds__(256) void k_head(const f16* __restrict__ h,
                                              const int* __restrict__ gstart,
                                              const int* __restrict__ gcount,
                                              const float* __restrict__ Wc,
                                              const float* __restrict__ bc,
                                              float* __restrict__ out, int G) {
    __shared__ float2 red[4][64];
    __shared__ float pl[HID];
    int g = blockIdx.x, t = threadIdx.x;
    int rr = t >> 6, cc = t & 63;
    int st = gstart[g], c = gcount[g];
    float2 acc = make_float2(0.f, 0.f);
    for (int i = rr; i < c; i += 4) {
        unsigned u = *(const unsigned*)&h[(size_t)(st + i) * HID + cc * 2];
        f16x2 v = __builtin_bit_cast(f16x2, u);
        acc.x += (float)v[0];
        acc.y += (float)v[1];
    }
    red[rr][cc] = acc;
    __syncthreads();
    if (rr == 0) {
        #pragma unroll
        for (int k = 1; k < 4; ++k) {
            acc.x += red[k][cc].x;
            acc.y += red[k][cc].y;
        }
        float inv = 1.f / fmaxf((float)c, 1.f);
        pl[cc * 2]     = acc.x * inv;
        pl[cc * 2 + 1] = acc.y * inv;
    }
    __syncthreads();
    if (t < NCLS) {
        float o = bc[t];
        for (int k = 0; k < HID; ++k) o += pl[k] * Wc[k * NCLS + t];
        out[g * NCLS + t] = o;
    }
}

// ---------------------------------------------------------------------------

static inline size_t alignup(size_t x, size_t a) { return (x + a - 1) & ~(a - 1); }

extern "C" void kernel_launch(void* const* d_in, const int* in_sizes, int n_in,
                              void* d_out, int out_size, void* d_ws, size_t ws_size,
                              hipStream_t stream) {
    const float* x      = (const float*)d_in[0];
    const int*   ei     = (const int*)d_in[1];
    const float* eattr  = (const float*)d_in[2];
    const int*   batch  = (const int*)d_in[3];
    const float* W1_0   = (const float*)d_in[4];
    const float* b1_0   = (const float*)d_in[5];
    const float* W2_0   = (const float*)d_in[6];
    const float* b2_0   = (const float*)d_in[7];
    const float* W1_s   = (const float*)d_in[8];
    const float* b1_s   = (const float*)d_in[9];
    const float* W2_s   = (const float*)d_in[10];
    const float* b2_s   = (const float*)d_in[11];
    const float* Wc     = (const float*)d_in[12];
    const float* bc     = (const float*)d_in[13];

    const int N = in_sizes[0];          // 100000
    const int E = in_sizes[2];          // 1600000
    const int G = out_size / NCLS;      // 1000
    const int* srcI = ei;
    const int* dstI = ei + E;

    const int NB = (N + BNODES - 1) >> BSHIFT;          // 391 buckets
    const int NBLK = (E + EPB - 1) / EPB;               // 391 binning blocks
    const int GSB = (N + 1023) / 1024;                  // 98 gseg blocks

    char* p = (char*)d_ws;
    size_t off = 0;
    size_t gcount_off = off;         off = alignup(off + (size_t)G * 4, 256);
    size_t gstart_off = off;         off = alignup(off + (size_t)G * 4, 256);
    size_t cursor_off = off;         off = alignup(off + 512 * 4, 256);
    size_t zero_bytes = off;
    size_t meta_off = off;           off = alignup(off + (size_t)N * 8, 256);
    size_t bbase_off = off;          off = alignup(off + 513 * 4, 256);
    size_t hin0_off = off;           off = alignup(off + (size_t)N * 4, 256);
    size_t wf_off = off;             off = alignup(off + 7 * 16384 * 2, 256);
    size_t pairs_off = off;          off = alignup(off + (size_t)NB * ECAP * 8, 256);
    size_t p0_off = off;             off = alignup(off + (size_t)N * HID * 2, 256);
    size_t p8_off = off;             off = alignup(off + (size_t)N * HID, 256);
    size_t p1_off = off;             off = alignup(off + (size_t)N * HID * 2, 256);

    int*    gcount  = (int*)(p + gcount_off);
    int*    gstart  = (int*)(p + gstart_off);
    int*    cursor  = (int*)(p + cursor_off);
    int2*   meta    = (int2*)(p + meta_off);
    int*    bbase   = (int*)(p + bbase_off);
    float*  hin0    = (float*)(p + hin0_off);
    f16*    Wf      = (f16*)(p + wf_off);
    int2*   pairs   = (int2*)(p + pairs_off);
    f16*    P0      = (f16*)(p + p0_off);
    unsigned char* P8 = (unsigned char*)(p + p8_off);
    f16*    P1      = (f16*)(p + p1_off);
    // ebuf aliases P1 (dead until layer-1's k_agg writes P1):
    // NB*ECAP*8B = 391*6400*8 = 20.0MB <= N*HID*2B = 25.6MB
    int2*   ebuf    = (int2*)(p + p1_off);

    hipMemsetAsync(d_ws, 0, zero_bytes, stream);

    int gblk = (N + 63) / 64;
    int abl = (N + 15) / 16;            // k_agg: 16 nodes per 256-thr block

    // merged: binning + W prefrag + graph-segment prep in one grid
    k_bin2m<<<NBLK + 14 + GSB, 1024, 0, stream>>>(
        srcI, dstI, eattr, x, cursor, ebuf,
        W2_0, W1_s, W2_s, Wf, batch, gcount, gstart,
        E, NB, NBLK, N);
    k_scan<<<1, 1024, 0, stream>>>(cursor, bbase, NB);
    k_fill2<<<NB, 512, 0, stream>>>(ebuf, cursor, bbase, x, meta,
                                    pairs, hin0, N);

    // Wf plane bases: g=0 -> W2_0; g=1+2l -> W1_s[l]; g=2+2l -> W2_s[l]
    #define WFG(g) (Wf + (size_t)(g) * 16384)

    // layer 0: rank1-expand + GEMM(W2_0) -> P0 (f16 + fp8 shadow)
    k_mlp0<<<gblk, 256, 0, stream>>>(hin0, W1_0, b1_0, WFG(0), b2_0,
                                     P0, P8, N);

    // layers 1..3: agg (P8 gather, P0 self -> P1) + MLP (P1 -> P0 [+P8])
    for (int l = 0; l < 3; ++l) {
        const float* b1 = b1_s + (size_t)l * HID;
        const float* b2 = b2_s + (size_t)l * HID;
        k_agg<<<abl, 256, 0, stream>>>(P8, P0, pairs, meta, P1, N);
        k_mlp<<<gblk, 256, 0, stream>>>(P1, WFG(1 + 2 * l), b1,
                                        WFG(2 + 2 * l), b2, P0, P8,
                                        (l < 2) ? 1 : 0, N);
    }

    k_head<<<G, 256, 0, stream>>>(P0, gstart, gcount, Wc, bc,
                                  (float*)d_out, G);
}

// Round 16
// 260.341 us; speedup vs baseline: 1.0916x; 1.0142x over previous
//
#include <hip/hip_runtime.h>
#include <hip/hip_bf16.h>

// ---------------------------------------------------------------------------
// GINE GNN. Features: f16 plane (self/MLP) + fp8-e4m3 shadow plane gathered
// by k_agg (r8 layout: wave = 4 nodes x 16 lanes, 16-deep gather pipeline).
// CSR: single-pass bucket binning (256-node buckets, line-aligned
// reservations, EPB 4096) with W-prefrag + graph-segment prep merged as
// role-blocks (r15, hide under latency-bound binning); per-bucket sort
// (512 thr) with register staging + direct pairs writes into FIXED
// per-bucket regions (r16: pstart = b*ECAP, same scheme as ebuf -- deletes
// the global scan kernel + bbase; address gaps cost nothing). MLP epilogues
// vectorized via swizzled-LDS -> f16x8 + packed-fp8 (r13).
// Lessons: r2/r11 = cross-XCD fine-grain scatter/atomics in hot per-edge
// paths kill; r4 = never trade reg accumulation for LDS atomics; r8 =
// gather MLP depth is the agg lever; r9 = agg+MLP fusion net-neutral;
// r10/r12 = line-dense reservations + all-CU grids fixed bin2; r13 =
// vector epilogues; r14 = block-TLP saturated at EPB 4096; r15 = role-
// block merging hides independent prep work.
// ---------------------------------------------------------------------------

#define HID 128
#define NCLS 3
#define EPB 4096          // edges per binning block (391 blocks, all CUs)
#define BSHIFT 8          // bucket = dst >> 8 (256 nodes/bucket)
#define BNODES 256
#define ECAP 6400         // slots per bucket (mean padded ~5490, +11 sigma)

typedef _Float16 f16;
typedef f16 f16x2 __attribute__((ext_vector_type(2)));
typedef f16 f16x8 __attribute__((ext_vector_type(8)));
typedef float f32x2 __attribute__((ext_vector_type(2)));
typedef float f32x4 __attribute__((ext_vector_type(4)));
typedef unsigned short ushort;

__device__ __forceinline__ float bcf(int v) {
    return __builtin_bit_cast(float, v);
}
__device__ __forceinline__ float f16bits2f(ushort u) {
    return (float)__builtin_bit_cast(f16, u);
}

// ---- merged: binning + W prefrag + graph-segment prep (role-blocks) -------
// blocks [0,NBLK): CSR binning -- ONE pass count+reserve(line-aligned)+place
//   ebuf slot: x = src | (dstlocal<<24), y = (attr_f16<<16) | msg0_f16
// blocks [NBLK,NBLK+14): W prefragmentation (f16 per-lane MFMA layout)
// blocks [NBLK+14,...): graph-segment prep (gcount/gstart from batch)

__global__ __launch_bounds__(1024) void k_bin2m(
    const int* __restrict__ src, const int* __restrict__ dst,
    const float* __restrict__ eattr, const float* __restrict__ x,
    int* __restrict__ cursor, int2* __restrict__ ebuf,
    const float* __restrict__ W2_0, const float* __restrict__ W1_s,
    const float* __restrict__ W2_s, f16* __restrict__ Wf,
    const int* __restrict__ batch, int* __restrict__ gcount,
    int* __restrict__ gstart,
    int E, int NB, int NBLK, int N) {

    __shared__ int lh[512];
    __shared__ int lbase[512];
    __shared__ int lrsv[512];
    int t = threadIdx.x;

    if (blockIdx.x < (unsigned)NBLK) {
        // ---------------- binning role ----------------
        if (t < NB) lh[t] = 0;
        __syncthreads();
        int base = blockIdx.x * EPB;
        int myd[4];
        #pragma unroll
        for (int j = 0; j < 4; ++j) {
            int e = base + j * 1024 + t;
            myd[j] = (e < E) ? dst[e] : -1;
            if (myd[j] >= 0) atomicAdd(&lh[myd[j] >> BSHIFT], 1);
        }
        __syncthreads();
        if (t < NB) {
            int c = lh[t];
            int cp = (c + 7) & ~7;           // 64B-line-aligned reservation
            lrsv[t] = cp;
            lbase[t] = (cp > 0) ? (t * ECAP + atomicAdd(&cursor[t], cp)) : 0;
            lh[t] = 0;
        }
        __syncthreads();
        #pragma unroll
        for (int j = 0; j < 4; ++j) {
            if (myd[j] >= 0) {
                int e = base + j * 1024 + t;
                int b = myd[j] >> BSHIFT;
                int s = src[e];
                float at = eattr[e];
                float msg = fmaxf(x[s] + at, 0.f);   // layer-0 message
                unsigned a16 = __builtin_bit_cast(ushort, (f16)at);
                unsigned m16 = __builtin_bit_cast(ushort, (f16)msg);
                int r = atomicAdd(&lh[b], 1);
                int pos = lbase[b] + r;
                if (pos < (b + 1) * ECAP)      // overflow guard (never hits)
                    ebuf[pos] = make_int2(s | ((myd[j] & (BNODES - 1)) << 24),
                                          (int)((a16 << 16) | m16));
            }
        }
        __syncthreads();
        // sentinel-fill this block's padding (<=7 per bucket, own lines)
        if (t < NB) {
            int c = lh[t], cp = lrsv[t];
            int p0 = lbase[t] + c;
            int pe = lbase[t] + cp;
            int cap = (t + 1) * ECAP;
            if (pe > cap) pe = cap;
            for (int pos = p0; pos < pe; ++pos)
                ebuf[pos] = make_int2(-1, 0);
        }
    } else if (blockIdx.x < (unsigned)(NBLK + 14)) {
        // ---------------- W prefragmentation role ----------------
        int id = (blockIdx.x - NBLK) * 1024 + t;     // [0, 14336)
        int lane = id & 63;
        int w    = (id >> 6) & 3;
        int nf   = (id >> 8) & 1;
        int kk   = (id >> 9) & 3;
        int g    = id >> 11;
        const float* W = (g == 0) ? W2_0
                       : ((g & 1) ? W1_s + (size_t)((g - 1) >> 1) * HID * HID
                                  : W2_s + (size_t)((g - 2) >> 1) * HID * HID);
        int col = w * 32 + nf * 16 + (lane & 15);
        int k0  = kk * 32 + (lane >> 4) * 8;
        f16x8 hi;
        #pragma unroll
        for (int j = 0; j < 8; ++j)
            hi[j] = (f16)W[(k0 + j) * HID + col];
        size_t o = ((((size_t)g * 4 + kk) * 2 + nf) * 4 + w) * 512 +
                   (size_t)lane * 8;
        *(f16x8*)&Wf[o] = hi;
    } else {
        // ---------------- graph-segment role ----------------
        int i = (blockIdx.x - NBLK - 14) * 1024 + t;
        if (i < N) {
            int gb = batch[i];
            atomicAdd(&gcount[gb], 1);
            if (i == 0 || batch[i - 1] != gb) gstart[gb] = i;
        }
    }
}

// per-bucket (256 nodes): global read into REGISTERS (<=13 slots per thread,
// statically unrolled); skip sentinels; count via LDS atomics; scan of 256
// counters by wave 0 via shfl (4 counters/lane); place DIRECTLY to global
// pairs at FIXED per-bucket base b*ECAP (block-exclusive region ->
// L2-absorbed, written back once; no global scan needed).
// pairs.x = src*128 byte offset (fp8 plane); pairs.y = f32 attr bits.
__global__ __launch_bounds__(512, 8) void k_fill2(const int2* __restrict__ ebuf,
                                               const int* __restrict__ btot,
                                               const float* __restrict__ x,
                                               int2* __restrict__ meta,
                                               int2* __restrict__ pairs,
                                               float* __restrict__ hin0,
                                               int N) {
    __shared__ int lcnt[BNODES];
    __shared__ int lofs[BNODES];
    __shared__ float satom[BNODES];
    int b = blockIdx.x, t = threadIdx.x;
    int estart = b * ECAP;
    int cnt = min(btot[b], ECAP);
    int pstart = b * ECAP;               // fixed region, same stride as ebuf
    int nb0 = b << BSHIFT;
    if (t < BNODES) {
        lcnt[t] = 0;
        satom[t] = 0.f;
    }
    __syncthreads();
    // load slots into registers: 13 independent loads in flight, then count
    int2 myv[13];
    #pragma unroll
    for (int j = 0; j < 13; ++j) {
        int i = j * 512 + t;
        if (i < cnt) myv[j] = ebuf[estart + i];
    }
    #pragma unroll
    for (int j = 0; j < 13; ++j) {
        int i = j * 512 + t;
        if (i < cnt && myv[j].x != -1)
            atomicAdd(&lcnt[((unsigned)myv[j].x) >> 24], 1);
    }
    __syncthreads();
    // wave 0 scans the 256 counters via shfl (4 counters/lane)
    if (t < 64) {
        int c0 = lcnt[4 * t], c1 = lcnt[4 * t + 1];
        int c2 = lcnt[4 * t + 2], c3 = lcnt[4 * t + 3];
        int s = c0 + c1 + c2 + c3;
        int sa = s;
        #pragma unroll
        for (int o = 1; o < 64; o <<= 1) {
            int v = __shfl_up(sa, o);
            if (t >= o) sa += v;
        }
        int e0 = sa - s;                      // exclusive lane base
        int e1 = e0 + c0, e2 = e1 + c1, e3 = e2 + c2;
        lofs[4 * t] = e0; lofs[4 * t + 1] = e1;
        lofs[4 * t + 2] = e2; lofs[4 * t + 3] = e3;
        lcnt[4 * t] = 0; lcnt[4 * t + 1] = 0;
        lcnt[4 * t + 2] = 0; lcnt[4 * t + 3] = 0;
        int n0 = nb0 + 4 * t;
        if (n0 < N)     meta[n0]     = make_int2(pstart + e0, c0);
        if (n0 + 1 < N) meta[n0 + 1] = make_int2(pstart + e1, c1);
        if (n0 + 2 < N) meta[n0 + 2] = make_int2(pstart + e2, c2);
        if (n0 + 3 < N) meta[n0 + 3] = make_int2(pstart + e3, c3);
    }
    __syncthreads();
    // place: direct global write (region is block-exclusive, L2-resident);
    // satom adds the precomputed f16 message
    #pragma unroll
    for (int j = 0; j < 13; ++j) {
        int i = j * 512 + t;
        if (i < cnt) {
            int2 v = myv[j];
            if (v.x != -1) {
                int ld = ((unsigned)v.x) >> 24;
                int srcid = v.x & 0x00FFFFFF;
                ushort a16 = (ushort)(((unsigned)v.y) >> 16);
                ushort m16 = (ushort)(v.y & 0xFFFF);
                int r = atomicAdd(&lcnt[ld], 1);
                int pos = lofs[ld] + r;
                pairs[pstart + pos] = make_int2(srcid << 7,
                                     __builtin_bit_cast(int, f16bits2f(a16)));
                atomicAdd(&satom[ld], f16bits2f(m16));
            }
        }
    }
    __syncthreads();
    if (t < BNODES) {
        int node = nb0 + t;
        if (node < N) hin0[node] = x[node] + satom[t];
    }
}

// ---- aggregation: wave = 4 nodes x 16 lanes, 16-deep gather pipeline ------

__device__ __forceinline__ void agg_add8(f32x2 acc2[4], uint2 g, float e) {
    f32x2 e2 = {e, e}, z2 = {0.f, 0.f};
    unsigned gw[2] = {g.x, g.y};
    #pragma unroll
    for (int ww = 0; ww < 2; ++ww) {
        f32x2 lo = __builtin_amdgcn_cvt_pk_f32_fp8((int)gw[ww], false);
        f32x2 hi = __builtin_amdgcn_cvt_pk_f32_fp8((int)gw[ww], true);
        lo = __builtin_elementwise_max(lo + e2, z2);
        hi = __builtin_elementwise_max(hi + e2, z2);
        acc2[2 * ww]     += lo;
        acc2[2 * ww + 1] += hi;
    }
}

__device__ __forceinline__ uint2 agg_ld8(const char* __restrict__ hb,
                                         int voff) {
    return *(const uint2*)(hb + (unsigned)voff);
}

__global__ __launch_bounds__(256, 4) void k_agg(
    const unsigned char* __restrict__ h8,
    const f16* __restrict__ hf,
    const int2* __restrict__ pairs,
    const int2* __restrict__ meta,
    f16* __restrict__ oh, int n) {

    int t = threadIdx.x;
    int w = t >> 6, lane = t & 63;
    int g = lane >> 4, c = lane & 15;
    int node = blockIdx.x * 16 + w * 4 + g;
    int c8 = c * 8;
    int sbase = g * 16;
    const char* hb = (const char*)h8;

    int2 m = make_int2(0, 0);
    if (node < n) m = meta[node];
    int off = m.x, d = m.y;
    f32x2 acc2[4] = {{0.f,0.f},{0.f,0.f},{0.f,0.f},{0.f,0.f}};

    for (int wb = 0; wb < d; wb += 16) {
        int rem = d - wb;
        int mm = rem < 16 ? rem : 16;
        int2 pr = make_int2(0, 0);
        if (c < mm) pr = pairs[off + wb + c];
        uint2 gg[16];
        #pragma unroll
        for (int p = 0; p < 16; ++p) {
            int s = __shfl(pr.x, sbase + p);
            if (p < mm) gg[p] = agg_ld8(hb, s + c8);
        }
        #pragma unroll
        for (int p = 0; p < 16; ++p) {
            if (p < mm) {
                float e = bcf(__shfl(pr.y, sbase + p));
                agg_add8(acc2, gg[p], e);
            }
        }
    }

    if (node < n) {
        uint4 sg = *(const uint4*)&hf[(size_t)node * HID + c8];
        unsigned sw[4] = {sg.x, sg.y, sg.z, sg.w};
        unsigned ow[4];
        #pragma unroll
        for (int ww = 0; ww < 4; ++ww) {
            f16x2 s = __builtin_bit_cast(f16x2, sw[ww]);
            f16x2 o;
            o[0] = (f16)((float)s[0] + acc2[ww].x);
            o[1] = (f16)((float)s[1] + acc2[ww].y);
            ow[ww] = __builtin_bit_cast(unsigned, o);
        }
        uint4 o4;
        o4.x = ow[0]; o4.y = ow[1]; o4.z = ow[2]; o4.w = ow[3];
        *(uint4*)&oh[(size_t)node * HID + c8] = o4;
    }
}

// ---- MLP helpers (single-product f16 weights) -----------------------------

__device__ __forceinline__ void load_wfrags1(const f16* __restrict__ Wfg,
                                             int w, int lane,
                                             f16x8 whf[4][2]) {
    #pragma unroll
    for (int kk = 0; kk < 4; ++kk)
        #pragma unroll
        for (int nf = 0; nf < 2; ++nf) {
            size_t o = (((size_t)kk * 2 + nf) * 4 + w) * 512 +
                       (size_t)lane * 8;
            whf[kk][nf] = *(const f16x8*)&Wfg[o];
        }
}

__device__ __forceinline__ void do_gemm1(const f16* Ah,
                                         const f16x8 whf[4][2],
                                         int lane, f32x4 acc[4][2]) {
    int arow = lane & 15, akgrp = lane >> 4;
    #pragma unroll
    for (int kk = 0; kk < 4; ++kk) {
        int chunk = kk * 4 + akgrp;
        f16x8 ah[4];
        #pragma unroll
        for (int mf = 0; mf < 4; ++mf) {
            int r = mf * 16 + arow;
            int swz = chunk ^ (r & 15);
            ah[mf] = *(const f16x8*)&Ah[r * HID + swz * 8];
        }
        #pragma unroll
        for (int mf = 0; mf < 4; ++mf)
            #pragma unroll
            for (int nf = 0; nf < 2; ++nf)
                acc[mf][nf] = __builtin_amdgcn_mfma_f32_16x16x32_f16(
                    ah[mf], whf[kk][nf], acc[mf][nf], 0, 0, 0);
    }
}

// vectorized output: acc -> swizzled LDS -> f16x8 + packed-fp8 stores.
// Caller must barrier AFTER do_gemm1 (A reads done) before calling.
__device__ __forceinline__ void store_out_vec(
    f16* __restrict__ bufA, const f32x4 acc[4][2],
    float bv0, float bv1,
    int t, int wcol, int fcol, int kgrp, int row0,
    f16* __restrict__ O, unsigned char* __restrict__ O8, int w8, int n) {

    #pragma unroll
    for (int mf = 0; mf < 4; ++mf)
        #pragma unroll
        for (int nf = 0; nf < 2; ++nf) {
            int cc = wcol + nf * 16 + fcol;
            float bb = nf ? bv1 : bv0;
            #pragma unroll
            for (int j = 0; j < 4; ++j) {
                int r = mf * 16 + kgrp * 4 + j;
                float v = fmaxf(acc[mf][nf][j] + bb, 0.f);
                int addr = r * HID + (((cc >> 3) ^ (r & 15)) << 3) + (cc & 7);
                bufA[addr] = (f16)v;
            }
        }
    __syncthreads();
    #pragma unroll
    for (int rep = 0; rep < 4; ++rep) {
        int task = rep * 256 + t;
        int r = task >> 4, ch = task & 15;
        int gr = row0 + r;
        if (gr < n) {
            int swz = ch ^ (r & 15);
            f16x8 hv = *(const f16x8*)&bufA[r * HID + swz * 8];
            *(f16x8*)&O[(size_t)gr * HID + ch * 8] = hv;
            if (w8) {
                int pk0 = __builtin_amdgcn_cvt_pk_fp8_f32(
                    (float)hv[0], (float)hv[1], 0, false);
                pk0 = __builtin_amdgcn_cvt_pk_fp8_f32(
                    (float)hv[2], (float)hv[3], pk0, true);
                int pk1 = __builtin_amdgcn_cvt_pk_fp8_f32(
                    (float)hv[4], (float)hv[5], 0, false);
                pk1 = __builtin_amdgcn_cvt_pk_fp8_f32(
                    (float)hv[6], (float)hv[7], pk1, true);
                uint2 o8v = make_uint2((unsigned)pk0, (unsigned)pk1);
                *(uint2*)&O8[(size_t)gr * HID + ch * 8] = o8v;
            }
        }
    }
}

// ---- MLP: O = relu(relu(A@W1+b1)@W2+b2), A f16 plane; fp8 shadow write ----

__global__ __launch_bounds__(256, 3) void k_mlp(
    const f16* __restrict__ A_g,
    const f16* __restrict__ Wf1, const float* __restrict__ b1,
    const f16* __restrict__ Wf2, const float* __restrict__ b2,
    f16* __restrict__ O, unsigned char* __restrict__ O8, int w8, int n) {

    __shared__ __align__(16) f16 bufA[64 * HID];   // A, then T, then out
    int t = threadIdx.x, w = t >> 6, lane = t & 63;
    int wcol = w * 32, fcol = lane & 15, kgrp = lane >> 4;
    int row0 = blockIdx.x * 64;

    #pragma unroll
    for (int rep = 0; rep < 4; ++rep) {
        int task = rep * 256 + t;
        int r = task >> 4, ch = task & 15;
        int gr = min(row0 + r, n - 1);
        int swz = ch ^ (r & 15);
        *(f16x8*)&bufA[r * HID + swz * 8] =
            *(const f16x8*)&A_g[(size_t)gr * HID + ch * 8];
    }

    f32x4 acc[4][2];
    {
        f16x8 whf[4][2];
        load_wfrags1(Wf1, w, lane, whf);
        float bv0 = b1[wcol + fcol], bv1 = b1[wcol + 16 + fcol];
        __syncthreads();
        #pragma unroll
        for (int mf = 0; mf < 4; ++mf)
            #pragma unroll
            for (int nf = 0; nf < 2; ++nf)
                acc[mf][nf] = (f32x4)(0.f);
        do_gemm1(bufA, whf, lane, acc);
        __syncthreads();   // all A reads done before T overwrites
        #pragma unroll
        for (int mf = 0; mf < 4; ++mf)
            #pragma unroll
            for (int nf = 0; nf < 2; ++nf) {
                int cc = wcol + nf * 16 + fcol;
                float bb = nf ? bv1 : bv0;
                #pragma unroll
                for (int j = 0; j < 4; ++j) {
                    int r = mf * 16 + kgrp * 4 + j;
                    float v = fmaxf(acc[mf][nf][j] + bb, 0.f);
                    int addr = r * HID + (((cc >> 3) ^ (r & 15)) << 3) + (cc & 7);
                    bufA[addr] = (f16)v;
                }
            }
    }
    {
        f16x8 whf[4][2];
        load_wfrags1(Wf2, w, lane, whf);
        float bv0 = b2[wcol + fcol], bv1 = b2[wcol + 16 + fcol];
        __syncthreads();
        #pragma unroll
        for (int mf = 0; mf < 4; ++mf)
            #pragma unroll
            for (int nf = 0; nf < 2; ++nf)
                acc[mf][nf] = (f32x4)(0.f);
        do_gemm1(bufA, whf, lane, acc);
        __syncthreads();   // all T reads done before outputs overwrite
        store_out_vec(bufA, acc, bv0, bv1, t, wcol, fcol, kgrp, row0,
                      O, O8, w8, n);
    }
}

// ---- layer-0 MLP (rank-1 expansion fused) ---------------------------------

__global__ __launch_bounds__(256, 3) void k_mlp0(
    const float* __restrict__ r1x, const float* __restrict__ r1w,
    const float* __restrict__ r1b,
    const f16* __restrict__ Wf2, const float* __restrict__ b2,
    f16* __restrict__ O, unsigned char* __restrict__ O8, int n) {

    __shared__ __align__(16) f16 bufA[64 * HID];
    int t = threadIdx.x, w = t >> 6, lane = t & 63;
    int wcol = w * 32, fcol = lane & 15, kgrp = lane >> 4;
    int row0 = blockIdx.x * 64;

    #pragma unroll
    for (int rep = 0; rep < 4; ++rep) {
        int task = rep * 256 + t;
        int r = task >> 4, ch = task & 15;
        int gr = min(row0 + r, n - 1);
        int swz = ch ^ (r & 15);
        float xv = r1x[gr];
        f16x8 hi;
        #pragma unroll
        for (int j = 0; j < 8; ++j)
            hi[j] = (f16)fmaxf(xv * r1w[ch * 8 + j] + r1b[ch * 8 + j], 0.f);
        *(f16x8*)&bufA[r * HID + swz * 8] = hi;
    }

    f16x8 whf[4][2];
    load_wfrags1(Wf2, w, lane, whf);
    float bv0 = b2[wcol + fcol], bv1 = b2[wcol + 16 + fcol];
    __syncthreads();
    f32x4 acc[4][2];
    #pragma unroll
    for (int mf = 0; mf < 4; ++mf)
        #pragma unroll
        for (int nf = 0; nf < 2; ++nf)
            acc[mf][nf] = (f32x4)(0.f);
    do_gemm1(bufA, whf, lane, acc);
    __syncthreads();   // all A reads done before outputs overwrite
    store_out_vec(bufA, acc, bv0, bv1, t, wcol, fcol, kgrp, row0,
                  O, O8, 1, n);
}

// ---- mean pool + head: 256 threads, 4 rows in flight, f16x2 loads ---------

__global__ __launch_bounds__(256) void k_head(const f16* __restrict__ h,
                                              const int* __restrict__ gstart,
                                              const int* __restrict__ gcount,
                                              const float* __restrict__ Wc,
                                              const float* __restrict__ bc,
                                              float* __restrict__ out, int G) {
    __shared__ float2 red[4][64];
    __shared__ float pl[HID];
    int g = blockIdx.x, t = threadIdx.x;
    int rr = t >> 6, cc = t & 63;
    int st = gstart[g], c = gcount[g];
    float2 acc = make_float2(0.f, 0.f);
    for (int i = rr; i < c; i += 4) {
        unsigned u = *(const unsigned*)&h[(size_t)(st + i) * HID + cc * 2];
        f16x2 v = __builtin_bit_cast(f16x2, u);
        acc.x += (float)v[0];
        acc.y += (float)v[1];
    }
    red[rr][cc] = acc;
    __syncthreads();
    if (rr == 0) {
        #pragma unroll
        for (int k = 1; k < 4; ++k) {
            acc.x += red[k][cc].x;
            acc.y += red[k][cc].y;
        }
        float inv = 1.f / fmaxf((float)c, 1.f);
        pl[cc * 2]     = acc.x * inv;
        pl[cc * 2 + 1] = acc.y * inv;
    }
    __syncthreads();
    if (t < NCLS) {
        float o = bc[t];
        for (int k = 0; k < HID; ++k) o += pl[k] * Wc[k * NCLS + t];
        out[g * NCLS + t] = o;
    }
}

// ---------------------------------------------------------------------------

static inline size_t alignup(size_t x, size_t a) { return (x + a - 1) & ~(a - 1); }

extern "C" void kernel_launch(void* const* d_in, const int* in_sizes, int n_in,
                              void* d_out, int out_size, void* d_ws, size_t ws_size,
                              hipStream_t stream) {
    const float* x      = (const float*)d_in[0];
    const int*   ei     = (const int*)d_in[1];
    const float* eattr  = (const float*)d_in[2];
    const int*   batch  = (const int*)d_in[3];
    const float* W1_0   = (const float*)d_in[4];
    const float* b1_0   = (const float*)d_in[5];
    const float* W2_0   = (const float*)d_in[6];
    const float* b2_0   = (const float*)d_in[7];
    const float* W1_s   = (const float*)d_in[8];
    const float* b1_s   = (const float*)d_in[9];
    const float* W2_s   = (const float*)d_in[10];
    const float* b2_s   = (const float*)d_in[11];
    const float* Wc     = (const float*)d_in[12];
    const float* bc     = (const float*)d_in[13];

    const int N = in_sizes[0];          // 100000
    const int E = in_sizes[2];          // 1600000
    const int G = out_size / NCLS;      // 1000
    const int* srcI = ei;
    const int* dstI = ei + E;

    const int NB = (N + BNODES - 1) >> BSHIFT;          // 391 buckets
    const int NBLK = (E + EPB - 1) / EPB;               // 391 binning blocks
    const int GSB = (N + 1023) / 1024;                  // 98 gseg blocks

    char* p = (char*)d_ws;
    size_t off = 0;
    size_t gcount_off = off;         off = alignup(off + (size_t)G * 4, 256);
    size_t gstart_off = off;         off = alignup(off + (size_t)G * 4, 256);
    size_t cursor_off = off;         off = alignup(off + 512 * 4, 256);
    size_t zero_bytes = off;
    size_t meta_off = off;           off = alignup(off + (size_t)N * 8, 256);
    size_t hin0_off = off;           off = alignup(off + (size_t)N * 4, 256);
    size_t wf_off = off;             off = alignup(off + 7 * 16384 * 2, 256);
    size_t pairs_off = off;          off = alignup(off + (size_t)NB * ECAP * 8, 256);
    size_t p0_off = off;             off = alignup(off + (size_t)N * HID * 2, 256);
    size_t p8_off = off;             off = alignup(off + (size_t)N * HID, 256);
    size_t p1_off = off;             off = alignup(off + (size_t)N * HID * 2, 256);

    int*    gcount  = (int*)(p + gcount_off);
    int*    gstart  = (int*)(p + gstart_off);
    int*    cursor  = (int*)(p + cursor_off);
    int2*   meta    = (int2*)(p + meta_off);
    float*  hin0    = (float*)(p + hin0_off);
    f16*    Wf      = (f16*)(p + wf_off);
    int2*   pairs   = (int2*)(p + pairs_off);
    f16*    P0      = (f16*)(p + p0_off);
    unsigned char* P8 = (unsigned char*)(p + p8_off);
    f16*    P1      = (f16*)(p + p1_off);
    // ebuf aliases P1 (dead until layer-1's k_agg writes P1):
    // NB*ECAP*8B = 391*6400*8 = 20.0MB <= N*HID*2B = 25.6MB
    int2*   ebuf    = (int2*)(p + p1_off);

    hipMemsetAsync(d_ws, 0, zero_bytes, stream);

    int gblk = (N + 63) / 64;
    int abl = (N + 15) / 16;            // k_agg: 16 nodes per 256-thr block

    // merged: binning + W prefrag + graph-segment prep in one grid
    k_bin2m<<<NBLK + 14 + GSB, 1024, 0, stream>>>(
        srcI, dstI, eattr, x, cursor, ebuf,
        W2_0, W1_s, W2_s, Wf, batch, gcount, gstart,
        E, NB, NBLK, N);
    k_fill2<<<NB, 512, 0, stream>>>(ebuf, cursor, x, meta,
                                    pairs, hin0, N);

    // Wf plane bases: g=0 -> W2_0; g=1+2l -> W1_s[l]; g=2+2l -> W2_s[l]
    #define WFG(g) (Wf + (size_t)(g) * 16384)

    // layer 0: rank1-expand + GEMM(W2_0) -> P0 (f16 + fp8 shadow)
    k_mlp0<<<gblk, 256, 0, stream>>>(hin0, W1_0, b1_0, WFG(0), b2_0,
                                     P0, P8, N);

    // layers 1..3: agg (P8 gather, P0 self -> P1) + MLP (P1 -> P0 [+P8])
    for (int l = 0; l < 3; ++l) {
        const float* b1 = b1_s + (size_t)l * HID;
        const float* b2 = b2_s + (size_t)l * HID;
        k_agg<<<abl, 256, 0, stream>>>(P8, P0, pairs, meta, P1, N);
        k_mlp<<<gblk, 256, 0, stream>>>(P1, WFG(1 + 2 * l), b1,
                                        WFG(2 + 2 * l), b2, P0, P8,
                                        (l < 2) ? 1 : 0, N);
    }

    k_head<<<G, 256, 0, stream>>>(P0, gstart, gcount, Wc, bc,
                                  (float*)d_out, G);
}